// Round 4
// baseline (420.871 us; speedup 1.0000x reference)
//
#include <hip/hip_runtime.h>

// ---------------------------------------------------------------------------
// MultiheadAttention: T=1024, B=8, E=1024, H=16, HD=64, SCALE=0.125
// R9: T14 async-STAGE split in k_attn. R8 showed memory volume is ideal
//     (FETCH 81MB == hand-computed 80MB min) and occupancy 4w/SIMD gained
//     only 9% -> the bottleneck is the exposed global-load latency inside
//     the per-iter barrier pair (load->vmcnt->ds_write fully serial, x8).
//     Fix: reg-stage K/V one iter ahead (kreg/vreg = 16 VGPRs are the
//     second buffer; LDS stays 54272B/2 blocks/CU). Loads for iter i+1
//     issue right after the ds_writes of iter i and fly under the whole
//     compute phase (~1500+ cyc). Bias/mask prefetch for i+1 issues after
//     QK^T (current bfr dead), hidden under softmax+PV.
//     Reg budget: S32+Oacc16+kv16+bk<=32+aq8+ml8+addr~12 ~= 124 <= 128.
// ---------------------------------------------------------------------------

typedef __bf16 bf16x8 __attribute__((ext_vector_type(8)));
typedef float f32x4 __attribute__((ext_vector_type(4)));

#define LOG2E 1.4426950408889634f
#define QSCALE 0.18033688011112042f  // 0.125 * LOG2E

// round-to-nearest-even (one-time prep kernels)
static __device__ __forceinline__ unsigned short f2bf_rn(float f) {
  union { float f; unsigned u; } x;
  x.f = f;
  unsigned r = (x.u + 0x7fffu + ((x.u >> 16) & 1u)) >> 16;
  return (unsigned short)r;
}
// round-half-up (hot paths: 2 VALU ops)
static __device__ __forceinline__ unsigned short f2bf(float f) {
  union { float f; unsigned u; } x;
  x.f = f;
  return (unsigned short)((x.u + 0x8000u) >> 16);
}

static __device__ __forceinline__ void async_cp16(const void* g, void* l) {
  __builtin_amdgcn_global_load_lds((__attribute__((address_space(1))) void*)g,
                                   (__attribute__((address_space(3))) void*)l,
                                   16, 0, 0);
}

// ---------------- fp32 -> bf16 convert (query) ----------------
__global__ void k_cvt(const float* __restrict__ src, unsigned short* __restrict__ dst) {
  const int idx = blockIdx.x * 256 + threadIdx.x;
  const float4 f = ((const float4*)src)[idx];
  unsigned lo = (unsigned)f2bf_rn(f.x) | ((unsigned)f2bf_rn(f.y) << 16);
  unsigned hi = (unsigned)f2bf_rn(f.z) | ((unsigned)f2bf_rn(f.w) << 16);
  uint2 v; v.x = lo; v.y = hi;
  *(uint2*)(dst + (size_t)idx * 4) = v;
}

// ---------------- mask -> additive float (0 / -1e30) ----------------
__global__ void k_mask(const int* __restrict__ mask, float* __restrict__ Mfg) {
  const int i = blockIdx.x * 256 + threadIdx.x;  // 8192 total
  Mfg[i] = mask[i] ? -1e30f : 0.f;
}

// ---------------- transpose + convert weights: dst[e][d] = src[d][e] -------
__global__ void k_transw(const float* __restrict__ src, unsigned short* __restrict__ dst) {
  __shared__ float tile[32][33];
  const int bx = blockIdx.x << 5;
  const int by = blockIdx.y << 5;
  const int tx = threadIdx.x, ty = threadIdx.y;
#pragma unroll
  for (int i = 0; i < 32; i += 8)
    tile[ty + i][tx] = src[(size_t)(by + ty + i) * 1024 + bx + tx];
  __syncthreads();
#pragma unroll
  for (int i = 0; i < 32; i += 8)
    dst[(size_t)(bx + ty + i) * 1024 + by + tx] = f2bf_rn(tile[tx][ty + i]);
}

// ---------------- bias pretransform: fragment-layout bf16, log2 domain -----
__global__ __launch_bounds__(256, 2) void k_biasT(const float* __restrict__ bias,
                                                  unsigned short* __restrict__ B2) {
  __shared__ unsigned short tile[128 * 132];
  const int tid = threadIdx.x;
  const int ss = blockIdx.x, tt = blockIdx.y, h = blockIdx.z;
  const float* src = bias + ((long)h * 1024 + tt * 128) * 1024 + ss * 128;
#pragma unroll
  for (int c = 0; c < 16; ++c) {
    int flat = c * 256 + tid;
    int row = flat >> 5, col = (flat & 31) << 2;
    float4 v = *(const float4*)(src + (long)row * 1024 + col);
    unsigned short* t4 = &tile[row * 132 + col];
    t4[0] = f2bf_rn(v.x * LOG2E); t4[1] = f2bf_rn(v.y * LOG2E);
    t4[2] = f2bf_rn(v.z * LOG2E); t4[3] = f2bf_rn(v.w * LOG2E);
  }
  __syncthreads();
  const int wid = tid >> 6, lane = tid & 63, lanelo = lane & 15, quad = lane >> 4;
  unsigned short outv[64];
#pragma unroll
  for (int mi = 0; mi < 2; ++mi)
#pragma unroll
    for (int nj = 0; nj < 8; ++nj)
#pragma unroll
      for (int r = 0; r < 4; ++r)
        outv[mi * 32 + nj * 4 + r] =
            tile[(wid * 32 + mi * 16 + quad * 4 + r) * 132 + nj * 16 + lanelo];
  unsigned short* dst = B2 + ((((long)(h * 8 + tt) * 8 + ss) * 256 + tid) << 6);
#pragma unroll
  for (int i = 0; i < 8; ++i) ((uint4*)dst)[i] = ((const uint4*)outv)[i];
}

// ---------------- 128x128 bf16 GEMM mainloop (m97 structure) ----------------
static __device__ __forceinline__ void gemm_tile_128x128(
    const unsigned short* __restrict__ A, const unsigned short* __restrict__ Bt,
    int K, long m0, long n0,
    unsigned short* As, unsigned short* Bs, f32x4 acc[4][4]) {
  const int tid = threadIdx.x;
  const int wid = tid >> 6;
  const int lane = tid & 63;
  const int lanelo = lane & 15;
  const int quad = lane >> 4;
  const int wm = (wid >> 1) << 6;
  const int wn = (wid & 1) << 6;
  const int srow = tid >> 2;
  const int scol = (tid & 3) << 3;

  for (int k0 = 0; k0 < K; k0 += 32) {
    __syncthreads();
    {
      const unsigned short* ga0 = A + (m0 + srow) * K + k0 + scol;
      const unsigned short* ga1 = A + (m0 + srow + 64) * K + k0 + scol;
      const unsigned short* gb0 = Bt + (n0 + srow) * K + k0 + scol;
      const unsigned short* gb1 = Bt + (n0 + srow + 64) * K + k0 + scol;
      char* la = (char*)As + wid * 1024;
      char* lb = (char*)Bs + wid * 1024;
      async_cp16(ga0, la);
      async_cp16(ga1, la + 4096);
      async_cp16(gb0, lb);
      async_cp16(gb1, lb + 4096);
    }
    __syncthreads();
    bf16x8 a[4], b[4];
#pragma unroll
    for (int i = 0; i < 4; ++i) {
      a[i] = *(const bf16x8*)(As + (wm + i * 16 + lanelo) * 32 + quad * 8);
      b[i] = *(const bf16x8*)(Bs + (wn + i * 16 + lanelo) * 32 + quad * 8);
    }
#pragma unroll
    for (int i = 0; i < 4; ++i)
#pragma unroll
      for (int j = 0; j < 4; ++j)
        acc[i][j] = __builtin_amdgcn_mfma_f32_16x16x32_bf16(a[i], b[j], acc[i][j], 0, 0, 0);
  }
}

// ---------------- QKV GEMM with scatter epilogue ----------------
// Qh/Kh: [bh][t][64] bf16 (Q pre-scaled by 0.125*LOG2E); Vt: [bh][d][1024].
__global__ __launch_bounds__(256, 2) void k_gemm_qkv(
    const unsigned short* __restrict__ A, const unsigned short* __restrict__ Bt,
    unsigned short* __restrict__ Qh, unsigned short* __restrict__ Kh,
    unsigned short* __restrict__ Vt) {
  __shared__ unsigned short smem[9216];  // As(4096) + Bs(4096); V-epilogue reuses [128][72]
  unsigned short* As = smem;
  unsigned short* Bs = smem + 4096;
  f32x4 acc[4][4];
  const f32x4 z4 = {0.f, 0.f, 0.f, 0.f};
#pragma unroll
  for (int i = 0; i < 4; ++i)
#pragma unroll
    for (int j = 0; j < 4; ++j) acc[i][j] = z4;

  const long m0 = (long)blockIdx.y * 128;
  const long n0 = (long)blockIdx.x * 128;
  gemm_tile_128x128(A, Bt, 1024, m0, n0, As, Bs, acc);

  const int tid = threadIdx.x;
  const int wid = tid >> 6;
  const int lane = tid & 63;
  const int lanelo = lane & 15;
  const int quad = lane >> 4;
  const int wm = (wid >> 1) << 6;
  const int wn = (wid & 1) << 6;
  const int which = (int)(blockIdx.x >> 3);  // 0:Q 1:K 2:V

  if (which == 2) {
    // V epilogue: LDS transpose -> 32B-run coalesced stores into Vt[bh][d][1024]
    unsigned short* Vt_s = smem;  // [128][72]
    const long t0g = m0 >> 3;
#pragma unroll
    for (int half = 0; half < 2; ++half) {
      __syncthreads();
      if ((wid & 1) == half) {
#pragma unroll
        for (int mi = 0; mi < 4; ++mi)
#pragma unroll
          for (int nj = 0; nj < 4; ++nj)
#pragma unroll
            for (int r = 0; r < 4; ++r)
              Vt_s[(wm + mi * 16 + quad * 4 + r) * 72 + nj * 16 + lanelo] =
                  f2bf(acc[mi][nj][r]);
      }
      __syncthreads();
      const int h = (((int)(n0 & 1023)) >> 6) + half;
#pragma unroll
      for (int pp = 0; pp < 2; ++pp) {
        int p = tid + pp * 256;
        int b = p >> 6, d = p & 63;
        long off = ((long)(b * 16 + h)) << 16;
        __attribute__((aligned(16))) unsigned short vals[16];
#pragma unroll
        for (int t = 0; t < 16; ++t) vals[t] = Vt_s[(t * 8 + b) * 72 + d];
        uint4* dst = (uint4*)(Vt + off + (long)d * 1024 + t0g);
        dst[0] = ((const uint4*)vals)[0];
        dst[1] = ((const uint4*)vals)[1];
      }
    }
  } else {
#pragma unroll
    for (int mi = 0; mi < 4; ++mi)
#pragma unroll
      for (int nj = 0; nj < 4; ++nj)
#pragma unroll
        for (int r = 0; r < 4; ++r) {
          int m = (int)m0 + wm + mi * 16 + quad * 4 + r;
          int n = (int)n0 + wn + nj * 16 + lanelo;
          float v = acc[mi][nj][r];
          int t = m >> 3, b = m & 7;
          int e = n & 1023, h = e >> 6, d = e & 63;
          long off = ((long)(b * 16 + h)) << 16;
          if (which == 0)
            Qh[off + t * 64 + d] = f2bf(v * QSCALE);
          else
            Kh[off + t * 64 + d] = f2bf(v);
        }
  }
}

// ---------------- flash attention (log2-domain, 512 thr, T14 split-stage)
// grid: (128 bh, 8 t-tiles) — same-bh blocks share flat%8 -> same XCD L2.
__global__ __launch_bounds__(512, 4) void k_attn(
    const unsigned short* __restrict__ Qh, const unsigned short* __restrict__ Kh,
    const unsigned short* __restrict__ Vt, const unsigned short* __restrict__ B2,
    const float* __restrict__ Mfg, unsigned short* __restrict__ A2) {
  __shared__ unsigned short Ks[128 * 72];  // [s_loc][64+8 pad]   18432 B
  __shared__ unsigned short Vs[64 * 136];  // [d][128+8 pad]      17408 B
  __shared__ unsigned short Ps[128 * 72];  // [t_loc][64+8 pad]   18432 B

  const int tid = threadIdx.x;
  const int wid = tid >> 6;        // 0..7
  const int lane = tid & 63;
  const int lanelo = lane & 15;
  const int quad = lane >> 4;
  const int bh = blockIdx.x;
  const int b = bh >> 4, h = bh & 15;
  const int tt = blockIdx.y;
  const int t0 = tt * 128;
  const long head = (long)bh << 16;

  // -- per-thread staging geometry (constant across iters) --
  const int krow = tid >> 3, kcol = (tid & 7) << 3;       // K: 128x64, 2 rounds
  const int vrow = tid >> 4, vcol = (tid & 15) << 3;      // V: 64x128, 2 rounds
  const unsigned short* kg = Kh + head + (long)krow * 64 + kcol;
  const unsigned short* vg = Vt + head + (long)vrow * 1024 + vcol;
  unsigned short* kl = &Ks[krow * 72 + kcol];
  unsigned short* vl = &Vs[vrow * 136 + vcol];

  // Q fragments straight from global (pre-scaled by 0.125*LOG2E): 16 rows/wave
  bf16x8 aq[2];
#pragma unroll
  for (int ks = 0; ks < 2; ++ks)
    aq[ks] = *(const bf16x8*)(Qh + head +
                              (long)(t0 + wid * 16 + lanelo) * 64 +
                              ks * 32 + quad * 8);

  const f32x4 z4 = {0.f, 0.f, 0.f, 0.f};
  f32x4 Oacc[4];
#pragma unroll
  for (int dj = 0; dj < 4; ++dj) Oacc[dj] = z4;
  float mrow[4], lrow[4];
#pragma unroll
  for (int r = 0; r < 4; ++r) { mrow[r] = -1e30f; lrow[r] = 0.f; }

  // bias fragment base: B2 laid out for 256-thr blocks with 2 mi-frags/thread;
  // wave pair (wid>>1) = old wid, (wid&1) = old mi.
  const long biasbase = (((long)(h * 8 + tt) * 8) * 256 + (wid >> 1) * 64 + lane) * 64 +
                        (wid & 1) * 32;

  // -- prologue: prefetch tile 0 K/V into regs, bias/mask for iter 0 --
  uint4 kreg[2], vreg[2];
  kreg[0] = *(const uint4*)(kg);
  kreg[1] = *(const uint4*)(kg + 64 * 64);
  vreg[0] = *(const uint4*)(vg);
  vreg[1] = *(const uint4*)(vg + 32 * 1024);
  bf16x8 bfr[4];
  {
    const bf16x8* bp8 = (const bf16x8*)(B2 + biasbase);
#pragma unroll
    for (int i = 0; i < 4; ++i) bfr[i] = bp8[i];
  }
  float madd[8];
#pragma unroll
  for (int nj = 0; nj < 8; ++nj)
    madd[nj] = Mfg[(long)b * 1024 + nj * 16 + lanelo];

  for (int s0 = 0; s0 < 1024; s0 += 128) {
    __syncthreads();  // all waves done reading prev Ks/Vs
    // drain regs -> LDS (vmcnt ~0: loads issued a full compute phase ago)
    *(uint4*)kl = kreg[0];
    *(uint4*)(kl + 64 * 72) = kreg[1];
    *(uint4*)vl = vreg[0];
    *(uint4*)(vl + 32 * 136) = vreg[1];
    // issue next tile's K/V loads; they fly under the whole compute phase
    if (s0 < 896) {
      const long s1 = s0 + 128;
      kreg[0] = *(const uint4*)(kg + s1 * 64);
      kreg[1] = *(const uint4*)(kg + s1 * 64 + 64 * 64);
      vreg[0] = *(const uint4*)(vg + s1);
      vreg[1] = *(const uint4*)(vg + s1 + 32 * 1024);
    }
    __syncthreads();

    // S init = bias + mask (log2 domain), folded into MFMA C-operand:
    // masked columns start at ~-1e30 and underflow to 0 in exp2.
    f32x4 S[8];
#pragma unroll
    for (int nj = 0; nj < 8; ++nj)
#pragma unroll
      for (int r = 0; r < 4; ++r)
        S[nj][r] = (float)bfr[nj >> 1][(nj & 1) * 4 + r] + madd[nj];

    // S += Q K^T (log2 domain)
#pragma unroll
    for (int ks = 0; ks < 2; ++ks) {
      bf16x8 bk[8];
#pragma unroll
      for (int nj = 0; nj < 8; ++nj)
        bk[nj] = *(const bf16x8*)(Ks + (nj * 16 + lanelo) * 72 + ks * 32 + quad * 8);
#pragma unroll
      for (int nj = 0; nj < 8; ++nj)
        S[nj] = __builtin_amdgcn_mfma_f32_16x16x32_bf16(aq[ks], bk[nj], S[nj], 0, 0, 0);
    }

    // prefetch next iter's bias/mask (current bfr/madd dead after S init);
    // latency hidden under softmax + PV.
    if (s0 < 896) {
      const bf16x8* bp8 = (const bf16x8*)(B2 + biasbase + ((long)((s0 >> 7) + 1) * 256 << 6));
#pragma unroll
      for (int i = 0; i < 4; ++i) bfr[i] = bp8[i];
#pragma unroll
      for (int nj = 0; nj < 8; ++nj)
        madd[nj] = Mfg[(long)b * 1024 + s0 + 128 + nj * 16 + lanelo];
    }

    // online softmax per row (log2 domain; masked entries underflow to 0)
#pragma unroll
    for (int r = 0; r < 4; ++r) {
      float mx = S[0][r];
#pragma unroll
      for (int nj = 1; nj < 8; ++nj) mx = fmaxf(mx, S[nj][r]);
      mx = fmaxf(mx, __shfl_xor(mx, 1, 16));
      mx = fmaxf(mx, __shfl_xor(mx, 2, 16));
      mx = fmaxf(mx, __shfl_xor(mx, 4, 16));
      mx = fmaxf(mx, __shfl_xor(mx, 8, 16));
      float mold = mrow[r];
      float mnew = fmaxf(mold, mx);
      float al = exp2f(mold - mnew);
      mrow[r] = mnew;
      float rs = 0.f;
#pragma unroll
      for (int nj = 0; nj < 8; ++nj) {
        float p = exp2f(S[nj][r] - mnew);
        S[nj][r] = p;
        rs += p;
      }
      rs += __shfl_xor(rs, 1, 16);
      rs += __shfl_xor(rs, 2, 16);
      rs += __shfl_xor(rs, 4, 16);
      rs += __shfl_xor(rs, 8, 16);
      lrow[r] = lrow[r] * al + rs;
#pragma unroll
      for (int dj = 0; dj < 4; ++dj) Oacc[dj][r] *= al;
    }

    // O += P V, in two 64-col halves (P rows are wave-private: no barrier)
#pragma unroll
    for (int half = 0; half < 2; ++half) {
#pragma unroll
      for (int njl = 0; njl < 4; ++njl)
#pragma unroll
        for (int r = 0; r < 4; ++r)
          Ps[(wid * 16 + quad * 4 + r) * 72 + njl * 16 + lanelo] =
              f2bf(S[half * 4 + njl][r]);
#pragma unroll
      for (int ks2 = 0; ks2 < 2; ++ks2) {
        const int ks = half * 2 + ks2;
        bf16x8 ap, bv[4];
        ap = *(const bf16x8*)(Ps + (wid * 16 + lanelo) * 72 + ks2 * 32 + quad * 8);
#pragma unroll
        for (int dj = 0; dj < 4; ++dj)
          bv[dj] = *(const bf16x8*)(Vs + (dj * 16 + lanelo) * 136 + ks * 32 + quad * 8);
#pragma unroll
        for (int dj = 0; dj < 4; ++dj)
          Oacc[dj] = __builtin_amdgcn_mfma_f32_16x16x32_bf16(ap, bv[dj], Oacc[dj], 0, 0, 0);
      }
    }
  }

  // epilogue: A2[(t*8+b)*1024 + h*64 + d] = O / l
#pragma unroll
  for (int r = 0; r < 4; ++r) {
    float rinv = __builtin_amdgcn_rcpf(lrow[r]);
    int t = t0 + wid * 16 + quad * 4 + r;
#pragma unroll
    for (int dj = 0; dj < 4; ++dj) {
      int d = dj * 16 + lanelo;
      A2[(long)(t * 8 + b) * 1024 + h * 64 + d] = f2bf(Oacc[dj][r] * rinv);
    }
  }
}

// ---------------- out projection GEMM -> fp32 d_out ----------------
__global__ __launch_bounds__(256, 2) void k_gemm_out(
    const unsigned short* __restrict__ A, const unsigned short* __restrict__ Bt,
    float* __restrict__ out) {
  __shared__ unsigned short As[128 * 32];
  __shared__ unsigned short Bs[128 * 32];
  f32x4 acc[4][4];
  const f32x4 z4 = {0.f, 0.f, 0.f, 0.f};
#pragma unroll
  for (int i = 0; i < 4; ++i)
#pragma unroll
    for (int j = 0; j < 4; ++j) acc[i][j] = z4;

  const long m0 = (long)blockIdx.y * 128;
  const long n0 = (long)blockIdx.x * 128;
  gemm_tile_128x128(A, Bt, 1024, m0, n0, As, Bs, acc);

  const int tid = threadIdx.x;
  const int wid = tid >> 6;
  const int lane = tid & 63;
  const int lanelo = lane & 15;
  const int quad = lane >> 4;
  const int wm = (wid >> 1) << 6;
  const int wn = (wid & 1) << 6;
#pragma unroll
  for (int mi = 0; mi < 4; ++mi)
#pragma unroll
    for (int nj = 0; nj < 4; ++nj)
#pragma unroll
      for (int r = 0; r < 4; ++r) {
        long m = m0 + wm + mi * 16 + quad * 4 + r;
        long n = n0 + wn + nj * 16 + lanelo;
        out[m * 1024 + n] = acc[mi][nj][r];
      }
}

// ---------------- launch ----------------
extern "C" void kernel_launch(void* const* d_in, const int* in_sizes, int n_in,
                              void* d_out, int out_size, void* d_ws, size_t ws_size,
                              hipStream_t stream) {
  const float* query = (const float*)d_in[0];
  const int* mask = (const int*)d_in[1];
  const float* bias = (const float*)d_in[2];
  const float* wq = (const float*)d_in[3];
  const float* wk = (const float*)d_in[4];
  const float* wv = (const float*)d_in[5];
  const float* wo = (const float*)d_in[6];
  float* out = (float*)d_out;

  char* ws = (char*)d_ws;
  const size_t MB = 1024 * 1024;
  unsigned short* Abuf  = (unsigned short*)(ws);             // 16 MB
  unsigned short* WqkvT = (unsigned short*)(ws + 16 * MB);   // 6 MB
  unsigned short* WoT   = (unsigned short*)(ws + 22 * MB);   // 2 MB
  unsigned short* Qh    = (unsigned short*)(ws + 24 * MB);   // 16 MB
  unsigned short* Kh    = (unsigned short*)(ws + 40 * MB);   // 16 MB
  unsigned short* Vt    = (unsigned short*)(ws + 56 * MB);   // 16 MB
  unsigned short* A2    = (unsigned short*)(ws + 72 * MB);   // 16 MB
  unsigned short* B2    = (unsigned short*)(ws + 88 * MB);   // 32 MB
  float*          Mfg   = (float*)(ws + 120 * MB);           // 32 KB

  k_cvt<<<dim3(8192), dim3(256), 0, stream>>>(query, Abuf);
  k_mask<<<dim3(32), dim3(256), 0, stream>>>(mask, Mfg);
  dim3 tb(32, 8);
  k_transw<<<dim3(32, 32), tb, 0, stream>>>(wq, WqkvT);
  k_transw<<<dim3(32, 32), tb, 0, stream>>>(wk, WqkvT + 1024 * 1024);
  k_transw<<<dim3(32, 32), tb, 0, stream>>>(wv, WqkvT + 2 * 1024 * 1024);
  k_transw<<<dim3(32, 32), tb, 0, stream>>>(wo, WoT);
  k_biasT<<<dim3(8, 8, 16), dim3(256), 0, stream>>>(bias, B2);
  k_gemm_qkv<<<dim3(24, 64), dim3(256), 0, stream>>>(Abuf, WqkvT, Qh, Kh, Vt);
  k_attn<<<dim3(128, 8), dim3(512), 0, stream>>>(Qh, Kh, Vt, B2, Mfg, A2);
  k_gemm_out<<<dim3(8, 64), dim3(256), 0, stream>>>(A2, WoT, out);
}

// Round 5
// 383.590 us; speedup vs baseline: 1.0972x; 1.0972x over previous
//
#include <hip/hip_runtime.h>

// ---------------------------------------------------------------------------
// MultiheadAttention: T=1024, B=8, E=1024, H=16, HD=64, SCALE=0.125
// R10: zero-VGPR async staging for k_attn. R9 proved any reg-staged prefetch
//     spills (307MB scratch). Fix: global_load_lds (no VGPR round trip) with
//     LINEAR LDS tiles + pre-swizzled GLOBAL source addresses (G21/m173
//     both-sides pattern, chunk^row XOR) -> conflict-free ds_reads without
//     padding. Raw s_barrier + counted vmcnt (plain __syncthreads would
//     drain the prefetch): K_{i+1} issued at top of iter i (flies a full
//     iter); V_i issued at top, waited after QK^T+softmax (vmcnt(2) keeps
//     K in flight). Ps aliases Kcur (dead after QK^T; B3 orders it).
//     LDS = Kbuf0+Kbuf1+Vs = 48KB, 2 barriers/iter, 2 blocks/CU, regs = R8.
// ---------------------------------------------------------------------------

typedef __bf16 bf16x8 __attribute__((ext_vector_type(8)));
typedef float f32x4 __attribute__((ext_vector_type(4)));

#define LOG2E 1.4426950408889634f
#define QSCALE 0.18033688011112042f  // 0.125 * LOG2E

// round-to-nearest-even (one-time prep kernels)
static __device__ __forceinline__ unsigned short f2bf_rn(float f) {
  union { float f; unsigned u; } x;
  x.f = f;
  unsigned r = (x.u + 0x7fffu + ((x.u >> 16) & 1u)) >> 16;
  return (unsigned short)r;
}
// round-half-up (hot paths: 2 VALU ops)
static __device__ __forceinline__ unsigned short f2bf(float f) {
  union { float f; unsigned u; } x;
  x.f = f;
  return (unsigned short)((x.u + 0x8000u) >> 16);
}

static __device__ __forceinline__ void async_cp16(const void* g, void* l) {
  __builtin_amdgcn_global_load_lds((__attribute__((address_space(1))) void*)g,
                                   (__attribute__((address_space(3))) void*)l,
                                   16, 0, 0);
}

// ---------------- fp32 -> bf16 convert (query) ----------------
__global__ void k_cvt(const float* __restrict__ src, unsigned short* __restrict__ dst) {
  const int idx = blockIdx.x * 256 + threadIdx.x;
  const float4 f = ((const float4*)src)[idx];
  unsigned lo = (unsigned)f2bf_rn(f.x) | ((unsigned)f2bf_rn(f.y) << 16);
  unsigned hi = (unsigned)f2bf_rn(f.z) | ((unsigned)f2bf_rn(f.w) << 16);
  uint2 v; v.x = lo; v.y = hi;
  *(uint2*)(dst + (size_t)idx * 4) = v;
}

// ---------------- mask -> additive float (0 / -1e30) ----------------
__global__ void k_mask(const int* __restrict__ mask, float* __restrict__ Mfg) {
  const int i = blockIdx.x * 256 + threadIdx.x;  // 8192 total
  Mfg[i] = mask[i] ? -1e30f : 0.f;
}

// ---------------- transpose + convert weights: dst[e][d] = src[d][e] -------
__global__ void k_transw(const float* __restrict__ src, unsigned short* __restrict__ dst) {
  __shared__ float tile[32][33];
  const int bx = blockIdx.x << 5;
  const int by = blockIdx.y << 5;
  const int tx = threadIdx.x, ty = threadIdx.y;
#pragma unroll
  for (int i = 0; i < 32; i += 8)
    tile[ty + i][tx] = src[(size_t)(by + ty + i) * 1024 + bx + tx];
  __syncthreads();
#pragma unroll
  for (int i = 0; i < 32; i += 8)
    dst[(size_t)(bx + ty + i) * 1024 + by + tx] = f2bf_rn(tile[tx][ty + i]);
}

// ---------------- bias pretransform: fragment-layout bf16, log2 domain -----
__global__ __launch_bounds__(256, 2) void k_biasT(const float* __restrict__ bias,
                                                  unsigned short* __restrict__ B2) {
  __shared__ unsigned short tile[128 * 132];
  const int tid = threadIdx.x;
  const int ss = blockIdx.x, tt = blockIdx.y, h = blockIdx.z;
  const float* src = bias + ((long)h * 1024 + tt * 128) * 1024 + ss * 128;
#pragma unroll
  for (int c = 0; c < 16; ++c) {
    int flat = c * 256 + tid;
    int row = flat >> 5, col = (flat & 31) << 2;
    float4 v = *(const float4*)(src + (long)row * 1024 + col);
    unsigned short* t4 = &tile[row * 132 + col];
    t4[0] = f2bf_rn(v.x * LOG2E); t4[1] = f2bf_rn(v.y * LOG2E);
    t4[2] = f2bf_rn(v.z * LOG2E); t4[3] = f2bf_rn(v.w * LOG2E);
  }
  __syncthreads();
  const int wid = tid >> 6, lane = tid & 63, lanelo = lane & 15, quad = lane >> 4;
  unsigned short outv[64];
#pragma unroll
  for (int mi = 0; mi < 2; ++mi)
#pragma unroll
    for (int nj = 0; nj < 8; ++nj)
#pragma unroll
      for (int r = 0; r < 4; ++r)
        outv[mi * 32 + nj * 4 + r] =
            tile[(wid * 32 + mi * 16 + quad * 4 + r) * 132 + nj * 16 + lanelo];
  unsigned short* dst = B2 + ((((long)(h * 8 + tt) * 8 + ss) * 256 + tid) << 6);
#pragma unroll
  for (int i = 0; i < 8; ++i) ((uint4*)dst)[i] = ((const uint4*)outv)[i];
}

// ---------------- 128x128 bf16 GEMM mainloop (m97 structure) ----------------
static __device__ __forceinline__ void gemm_tile_128x128(
    const unsigned short* __restrict__ A, const unsigned short* __restrict__ Bt,
    int K, long m0, long n0,
    unsigned short* As, unsigned short* Bs, f32x4 acc[4][4]) {
  const int tid = threadIdx.x;
  const int wid = tid >> 6;
  const int lane = tid & 63;
  const int lanelo = lane & 15;
  const int quad = lane >> 4;
  const int wm = (wid >> 1) << 6;
  const int wn = (wid & 1) << 6;
  const int srow = tid >> 2;
  const int scol = (tid & 3) << 3;

  for (int k0 = 0; k0 < K; k0 += 32) {
    __syncthreads();
    {
      const unsigned short* ga0 = A + (m0 + srow) * K + k0 + scol;
      const unsigned short* ga1 = A + (m0 + srow + 64) * K + k0 + scol;
      const unsigned short* gb0 = Bt + (n0 + srow) * K + k0 + scol;
      const unsigned short* gb1 = Bt + (n0 + srow + 64) * K + k0 + scol;
      char* la = (char*)As + wid * 1024;
      char* lb = (char*)Bs + wid * 1024;
      async_cp16(ga0, la);
      async_cp16(ga1, la + 4096);
      async_cp16(gb0, lb);
      async_cp16(gb1, lb + 4096);
    }
    __syncthreads();
    bf16x8 a[4], b[4];
#pragma unroll
    for (int i = 0; i < 4; ++i) {
      a[i] = *(const bf16x8*)(As + (wm + i * 16 + lanelo) * 32 + quad * 8);
      b[i] = *(const bf16x8*)(Bs + (wn + i * 16 + lanelo) * 32 + quad * 8);
    }
#pragma unroll
    for (int i = 0; i < 4; ++i)
#pragma unroll
      for (int j = 0; j < 4; ++j)
        acc[i][j] = __builtin_amdgcn_mfma_f32_16x16x32_bf16(a[i], b[j], acc[i][j], 0, 0, 0);
  }
}

// ---------------- QKV GEMM with scatter epilogue ----------------
// Qh/Kh: [bh][t][64] bf16 (Q pre-scaled by 0.125*LOG2E); Vt: [bh][d][1024].
__global__ __launch_bounds__(256, 2) void k_gemm_qkv(
    const unsigned short* __restrict__ A, const unsigned short* __restrict__ Bt,
    unsigned short* __restrict__ Qh, unsigned short* __restrict__ Kh,
    unsigned short* __restrict__ Vt) {
  __shared__ unsigned short smem[9216];  // As(4096) + Bs(4096); V-epilogue reuses [128][72]
  unsigned short* As = smem;
  unsigned short* Bs = smem + 4096;
  f32x4 acc[4][4];
  const f32x4 z4 = {0.f, 0.f, 0.f, 0.f};
#pragma unroll
  for (int i = 0; i < 4; ++i)
#pragma unroll
    for (int j = 0; j < 4; ++j) acc[i][j] = z4;

  const long m0 = (long)blockIdx.y * 128;
  const long n0 = (long)blockIdx.x * 128;
  gemm_tile_128x128(A, Bt, 1024, m0, n0, As, Bs, acc);

  const int tid = threadIdx.x;
  const int wid = tid >> 6;
  const int lane = tid & 63;
  const int lanelo = lane & 15;
  const int quad = lane >> 4;
  const int wm = (wid >> 1) << 6;
  const int wn = (wid & 1) << 6;
  const int which = (int)(blockIdx.x >> 3);  // 0:Q 1:K 2:V

  if (which == 2) {
    // V epilogue: LDS transpose -> 32B-run coalesced stores into Vt[bh][d][1024]
    unsigned short* Vt_s = smem;  // [128][72]
    const long t0g = m0 >> 3;
#pragma unroll
    for (int half = 0; half < 2; ++half) {
      __syncthreads();
      if ((wid & 1) == half) {
#pragma unroll
        for (int mi = 0; mi < 4; ++mi)
#pragma unroll
          for (int nj = 0; nj < 4; ++nj)
#pragma unroll
            for (int r = 0; r < 4; ++r)
              Vt_s[(wm + mi * 16 + quad * 4 + r) * 72 + nj * 16 + lanelo] =
                  f2bf(acc[mi][nj][r]);
      }
      __syncthreads();
      const int h = (((int)(n0 & 1023)) >> 6) + half;
#pragma unroll
      for (int pp = 0; pp < 2; ++pp) {
        int p = tid + pp * 256;
        int b = p >> 6, d = p & 63;
        long off = ((long)(b * 16 + h)) << 16;
        __attribute__((aligned(16))) unsigned short vals[16];
#pragma unroll
        for (int t = 0; t < 16; ++t) vals[t] = Vt_s[(t * 8 + b) * 72 + d];
        uint4* dst = (uint4*)(Vt + off + (long)d * 1024 + t0g);
        dst[0] = ((const uint4*)vals)[0];
        dst[1] = ((const uint4*)vals)[1];
      }
    }
  } else {
#pragma unroll
    for (int mi = 0; mi < 4; ++mi)
#pragma unroll
      for (int nj = 0; nj < 4; ++nj)
#pragma unroll
        for (int r = 0; r < 4; ++r) {
          int m = (int)m0 + wm + mi * 16 + quad * 4 + r;
          int n = (int)n0 + wn + nj * 16 + lanelo;
          float v = acc[mi][nj][r];
          int t = m >> 3, b = m & 7;
          int e = n & 1023, h = e >> 6, d = e & 63;
          long off = ((long)(b * 16 + h)) << 16;
          if (which == 0)
            Qh[off + t * 64 + d] = f2bf(v * QSCALE);
          else
            Kh[off + t * 64 + d] = f2bf(v);
        }
  }
}

// ---------------- flash attention (log2 domain, 512 thr, async pipeline) ----
// grid: (128 bh, 8 t-tiles); tt-sharing blocks (same bh) land on one XCD ->
// K/V tiles are L2-resident for 7 of 8 readers.
// LDS: Kb0[128][64] | Kb1[128][64] | Vs[64][128], all LINEAR (gload_lds) with
// XOR-swizzled content: K/Ps chunk^=(row&7), V chunk^=(row&15). 48 KB.
__global__ __launch_bounds__(512, 4) void k_attn(
    const unsigned short* __restrict__ Qh, const unsigned short* __restrict__ Kh,
    const unsigned short* __restrict__ Vt, const unsigned short* __restrict__ B2,
    const float* __restrict__ Mfg, unsigned short* __restrict__ A2) {
  __shared__ unsigned short smem[24576];  // 48 KB
  unsigned short* Vs = smem + 16384;

  const int tid = threadIdx.x;
  const int wid = tid >> 6;        // 0..7
  const int lane = tid & 63;
  const int lanelo = lane & 15;
  const int quad = lane >> 4;
  const int bh = blockIdx.x;
  const int b = bh >> 4, h = bh & 15;
  const int tt = blockIdx.y;
  const int t0 = tt * 128;
  const long head = (long)bh << 16;

  // -- staging geometry (pre-swizzled global sources, linear LDS dests) --
  // K: wave w stages LDS rows [w*8,w*8+8) and [64+w*8,...); lane: row=l>>3,
  // chunk=l&7; content LDS[row][c]=K[row][c^(row&7)] -> src col (c^(l>>3))*8.
  const int krow0 = wid * 8 + (lane >> 3);
  const int ksw = (((lane & 7) ^ (lane >> 3)) << 3);
  const unsigned short* kg = Kh + head + (long)krow0 * 64 + ksw;
  // V: wave w call c: LDS row = c*32 + w*4 + (l>>4), chunk=l&15;
  // content LDS[row][c]=V[row][c^(row&15)] (row&15 same for both calls).
  const int vrow = wid * 4 + (lane >> 4);
  const int vsw = (((lane & 15) ^ (vrow & 15)) << 3);
  const unsigned short* vg = Vt + head + (long)vrow * 1024 + vsw;

  // prologue: issue K_0 into Kb0 (flies under aq/setup + first vmcnt(0))
  async_cp16(kg, (char*)smem + (wid << 10));
  async_cp16(kg + 64 * 64, (char*)smem + (wid << 10) + 8192);

  // Q fragments straight from global (pre-scaled by 0.125*LOG2E): 16 rows/wave
  bf16x8 aq[2];
#pragma unroll
  for (int ks = 0; ks < 2; ++ks)
    aq[ks] = *(const bf16x8*)(Qh + head +
                              (long)(t0 + wid * 16 + lanelo) * 64 +
                              ks * 32 + quad * 8);

  const f32x4 z4 = {0.f, 0.f, 0.f, 0.f};
  f32x4 Oacc[4];
#pragma unroll
  for (int dj = 0; dj < 4; ++dj) Oacc[dj] = z4;
  float mrow[4], lrow[4];
#pragma unroll
  for (int r = 0; r < 4; ++r) { mrow[r] = -1e30f; lrow[r] = 0.f; }

  // bias fragment base: B2 laid out for 256-thr blocks with 2 mi-frags/thread;
  // wave pair (wid>>1) = old wid, (wid&1) = old mi.
  const long biasbase = (((long)(h * 8 + tt) * 8) * 256 + (wid >> 1) * 64 + lane) * 64 +
                        (wid & 1) * 32;

  for (int it = 0; it < 8; ++it) {
    const int s0 = it << 7;
    unsigned short* Kcur = smem + ((it & 1) << 13);
    unsigned short* Kalt = smem + (((it + 1) & 1) << 13);

    // K_it landed (issued a full iteration ago; only K in flight here)
    asm volatile("s_waitcnt vmcnt(0)" ::: "memory");
    __builtin_amdgcn_s_barrier();          // B1: prev iter's LDS reads done
    __builtin_amdgcn_sched_barrier(0);

    // bias + mask loads for THIS iter (oldest VMEM of the iter)
    bf16x8 bfr[4];
    {
      const bf16x8* bp8 = (const bf16x8*)(B2 + biasbase + ((long)it * 256 << 6));
#pragma unroll
      for (int i = 0; i < 4; ++i) bfr[i] = bp8[i];
    }
    float madd[8];
#pragma unroll
    for (int nj = 0; nj < 8; ++nj)
      madd[nj] = Mfg[(long)b * 1024 + s0 + nj * 16 + lanelo];

    // stage V_it (waited at B3, hidden under QK^T+softmax)
    async_cp16(vg + s0, (char*)Vs + (wid << 10));
    async_cp16(vg + 32 * 1024 + s0, (char*)Vs + (wid << 10) + 8192);
    // prefetch K_{it+1} (waited at next iter's top; flies a full iteration)
    if (it < 7) {
      const unsigned short* kgs = kg + (long)(s0 + 128) * 64;
      async_cp16(kgs, (char*)Kalt + (wid << 10));
      async_cp16(kgs + 64 * 64, (char*)Kalt + (wid << 10) + 8192);
    }

    // S init = bias + mask (log2 domain), folded into MFMA C-operand:
    // masked columns start at ~-1e30 and underflow to 0 in exp2.
    f32x4 S[8];
#pragma unroll
    for (int nj = 0; nj < 8; ++nj)
#pragma unroll
      for (int r = 0; r < 4; ++r)
        S[nj][r] = (float)bfr[nj >> 1][(nj & 1) * 4 + r] + madd[nj];

    // S += Q K^T from Kcur (swizzled reads: 2 lanes/bank, conflict-free)
#pragma unroll
    for (int ks = 0; ks < 2; ++ks) {
      bf16x8 bk[8];
#pragma unroll
      for (int nj = 0; nj < 8; ++nj)
        bk[nj] = *(const bf16x8*)(Kcur + (nj * 16 + lanelo) * 64 +
                                  (((ks * 4 + quad) ^ (lanelo & 7)) << 3));
#pragma unroll
      for (int nj = 0; nj < 8; ++nj)
        S[nj] = __builtin_amdgcn_mfma_f32_16x16x32_bf16(aq[ks], bk[nj], S[nj], 0, 0, 0);
    }

    // online softmax per row (log2 domain; masked entries underflow to 0)
#pragma unroll
    for (int r = 0; r < 4; ++r) {
      float mx = S[0][r];
#pragma unroll
      for (int nj = 1; nj < 8; ++nj) mx = fmaxf(mx, S[nj][r]);
      mx = fmaxf(mx, __shfl_xor(mx, 1, 16));
      mx = fmaxf(mx, __shfl_xor(mx, 2, 16));
      mx = fmaxf(mx, __shfl_xor(mx, 4, 16));
      mx = fmaxf(mx, __shfl_xor(mx, 8, 16));
      float mold = mrow[r];
      float mnew = fmaxf(mold, mx);
      float al = exp2f(mold - mnew);
      mrow[r] = mnew;
      float rs = 0.f;
#pragma unroll
      for (int nj = 0; nj < 8; ++nj) {
        float p = exp2f(S[nj][r] - mnew);
        S[nj][r] = p;
        rs += p;
      }
      rs += __shfl_xor(rs, 1, 16);
      rs += __shfl_xor(rs, 2, 16);
      rs += __shfl_xor(rs, 4, 16);
      rs += __shfl_xor(rs, 8, 16);
      lrow[r] = lrow[r] * al + rs;
#pragma unroll
      for (int dj = 0; dj < 4; ++dj) Oacc[dj][r] *= al;
    }

    // V_it landed for this wave (vmcnt(2) keeps K_{it+1} in flight; count
    // robust: V is never among the 2 newest ops). Last iter: drain all.
    if (it < 7) asm volatile("s_waitcnt vmcnt(2)" ::: "memory");
    else        asm volatile("s_waitcnt vmcnt(0)" ::: "memory");
    __builtin_amdgcn_s_barrier();  // B3: all QK^T reads of Kcur done, V ready
    __builtin_amdgcn_sched_barrier(0);

    // Ps aliases Kcur (dead after B3): write P swizzled (chunk^(row&7)),
    // PV reads Vs (chunk^(row&15)). P rows are wave-private.
    unsigned short* Ps = Kcur;
#pragma unroll
    for (int half = 0; half < 2; ++half) {
#pragma unroll
      for (int njl = 0; njl < 4; ++njl)
#pragma unroll
        for (int r = 0; r < 4; ++r) {
          const int rw7 = ((quad << 2) + r) & 7;
          Ps[(wid * 16 + (quad << 2) + r) * 64 +
             ((((njl << 1) + (lanelo >> 3)) ^ rw7) << 3) + (lanelo & 7)] =
              f2bf(S[half * 4 + njl][r]);
        }
#pragma unroll
      for (int ks2 = 0; ks2 < 2; ++ks2) {
        const int ks = half * 2 + ks2;
        bf16x8 ap, bv[4];
        ap = *(const bf16x8*)(Ps + (wid * 16 + lanelo) * 64 +
                              (((ks2 * 4 + quad) ^ (lanelo & 7)) << 3));
#pragma unroll
        for (int dj = 0; dj < 4; ++dj)
          bv[dj] = *(const bf16x8*)(Vs + (dj * 16 + lanelo) * 128 +
                                    (((ks * 4 + quad) ^ lanelo) << 3));
#pragma unroll
        for (int dj = 0; dj < 4; ++dj)
          Oacc[dj] = __builtin_amdgcn_mfma_f32_16x16x32_bf16(ap, bv[dj], Oacc[dj], 0, 0, 0);
      }
    }
  }

  // epilogue: A2[(t*8+b)*1024 + h*64 + d] = O / l
#pragma unroll
  for (int r = 0; r < 4; ++r) {
    float rinv = __builtin_amdgcn_rcpf(lrow[r]);
    int t = t0 + wid * 16 + quad * 4 + r;
#pragma unroll
    for (int dj = 0; dj < 4; ++dj) {
      int d = dj * 16 + lanelo;
      A2[(long)(t * 8 + b) * 1024 + h * 64 + d] = f2bf(Oacc[dj][r] * rinv);
    }
  }
}

// ---------------- out projection GEMM -> fp32 d_out ----------------
__global__ __launch_bounds__(256, 2) void k_gemm_out(
    const unsigned short* __restrict__ A, const unsigned short* __restrict__ Bt,
    float* __restrict__ out) {
  __shared__ unsigned short As[128 * 32];
  __shared__ unsigned short Bs[128 * 32];
  f32x4 acc[4][4];
  const f32x4 z4 = {0.f, 0.f, 0.f, 0.f};
#pragma unroll
  for (int i = 0; i < 4; ++i)
#pragma unroll
    for (int j = 0; j < 4; ++j) acc[i][j] = z4;

  const long m0 = (long)blockIdx.y * 128;
  const long n0 = (long)blockIdx.x * 128;
  gemm_tile_128x128(A, Bt, 1024, m0, n0, As, Bs, acc);

  const int tid = threadIdx.x;
  const int wid = tid >> 6;
  const int lane = tid & 63;
  const int lanelo = lane & 15;
  const int quad = lane >> 4;
  const int wm = (wid >> 1) << 6;
  const int wn = (wid & 1) << 6;
#pragma unroll
  for (int mi = 0; mi < 4; ++mi)
#pragma unroll
    for (int nj = 0; nj < 4; ++nj)
#pragma unroll
      for (int r = 0; r < 4; ++r) {
        long m = m0 + wm + mi * 16 + quad * 4 + r;
        long n = n0 + wn + nj * 16 + lanelo;
        out[m * 1024 + n] = acc[mi][nj][r];
      }
}

// ---------------- launch ----------------
extern "C" void kernel_launch(void* const* d_in, const int* in_sizes, int n_in,
                              void* d_out, int out_size, void* d_ws, size_t ws_size,
                              hipStream_t stream) {
  const float* query = (const float*)d_in[0];
  const int* mask = (const int*)d_in[1];
  const float* bias = (const float*)d_in[2];
  const float* wq = (const float*)d_in[3];
  const float* wk = (const float*)d_in[4];
  const float* wv = (const float*)d_in[5];
  const float* wo = (const float*)d_in[6];
  float* out = (float*)d_out;

  char* ws = (char*)d_ws;
  const size_t MB = 1024 * 1024;
  unsigned short* Abuf  = (unsigned short*)(ws);             // 16 MB
  unsigned short* WqkvT = (unsigned short*)(ws + 16 * MB);   // 6 MB
  unsigned short* WoT   = (unsigned short*)(ws + 22 * MB);   // 2 MB
  unsigned short* Qh    = (unsigned short*)(ws + 24 * MB);   // 16 MB
  unsigned short* Kh    = (unsigned short*)(ws + 40 * MB);   // 16 MB
  unsigned short* Vt    = (unsigned short*)(ws + 56 * MB);   // 16 MB
  unsigned short* A2    = (unsigned short*)(ws + 72 * MB);   // 16 MB
  unsigned short* B2    = (unsigned short*)(ws + 88 * MB);   // 32 MB
  float*          Mfg   = (float*)(ws + 120 * MB);           // 32 KB

  k_cvt<<<dim3(8192), dim3(256), 0, stream>>>(query, Abuf);
  k_mask<<<dim3(32), dim3(256), 0, stream>>>(mask, Mfg);
  dim3 tb(32, 8);
  k_transw<<<dim3(32, 32), tb, 0, stream>>>(wq, WqkvT);
  k_transw<<<dim3(32, 32), tb, 0, stream>>>(wk, WqkvT + 1024 * 1024);
  k_transw<<<dim3(32, 32), tb, 0, stream>>>(wv, WqkvT + 2 * 1024 * 1024);
  k_transw<<<dim3(32, 32), tb, 0, stream>>>(wo, WoT);
  k_biasT<<<dim3(8, 8, 16), dim3(256), 0, stream>>>(bias, B2);
  k_gemm_qkv<<<dim3(24, 64), dim3(256), 0, stream>>>(Abuf, WqkvT, Qh, Kh, Vt);
  k_attn<<<dim3(128, 8), dim3(512), 0, stream>>>(Qh, Kh, Vt, B2, Mfg, A2);
  k_gemm_out<<<dim3(8, 64), dim3(256), 0, stream>>>(A2, WoT, out);
}